// Round 1
// baseline (168.414 us; speedup 1.0000x reference)
//
#include <hip/hip_runtime.h>

#define D 64
#define L 10
#define C 256

__device__ inline float wave_sum(float v) {
#pragma unroll
  for (int off = 32; off > 0; off >>= 1) v += __shfl_xor(v, off);
  return v;
}
__device__ inline float wave_max(float v) {
#pragma unroll
  for (int off = 32; off > 0; off >>= 1) v = fmaxf(v, __shfl_xor(v, off));
  return v;
}

// K = cluster_emb @ Wk, V = cluster_emb @ Wv  -> KV[0:C*D]=K, KV[C*D:2*C*D]=V
__global__ void kv_precompute(const float* __restrict__ cl,
                              const float* __restrict__ Wk,
                              const float* __restrict__ Wv,
                              float* __restrict__ KV) {
  int idx = blockIdx.x * blockDim.x + threadIdx.x;  // 0 .. 2*C*D-1
  if (idx >= 2 * C * D) return;
  int which = idx >> 14;            // C*D = 16384
  int cd = idx & (C * D - 1);
  int c = cd >> 6, d = cd & 63;
  const float* __restrict__ W = which ? Wv : Wk;
  float acc = 0.f;
#pragma unroll
  for (int k = 0; k < D; ++k) acc += cl[c * D + k] * W[k * D + d];
  KV[idx] = acc;
}

__global__ __launch_bounds__(256) void filter_main(
    const int* __restrict__ items,        // [U,L]
    const float* __restrict__ time_embs,  // [U,L,D]
    const float* __restrict__ ue_g,       // [U,D]
    const float* __restrict__ ie_g,       // [N,D]
    const float* __restrict__ wf_g,       // [U,L,D]
    const float* __restrict__ Wq,         // [D,D]
    const float* __restrict__ Kmat,       // [C,D]
    const float* __restrict__ Vmat,       // [C,D]
    const int* __restrict__ users,
    const int* __restrict__ pos_items,
    const int* __restrict__ neg_items,
    const float* __restrict__ a1p,
    const float* __restrict__ a2p,
    const float* __restrict__ a3p,
    float* __restrict__ out, int B) {
  __shared__ float s_ue[D];
  __shared__ int s_it[L];
  __shared__ float s_short[L][D];
  __shared__ float s_q[L][D];
  __shared__ float s_attn[L][C];
  __shared__ float s_red[L][4];
  __shared__ float s_shorted[L][D];
  __shared__ float s_sl[L];
  __shared__ float s_vt[64 * D];  // V tile [64][64]

  const int b = blockIdx.x;
  const int tid = threadIdx.x;
  const int w = tid >> 6;      // wave id 0..3
  const int lane = tid & 63;   // = d for per-dim phases
  const int u = users[b];
  const int BD = B * D;

  // fused pos/neg gathers (independent of everything else)
  if (tid >= 64 && tid < 128) {
    int p = pos_items[b];
    out[BD + b * D + (tid - 64)] = ie_g[p * D + (tid - 64)];
  } else if (tid >= 128 && tid < 192) {
    int p = neg_items[b];
    out[2 * BD + b * D + (tid - 128)] = ie_g[p * D + (tid - 128)];
  }

  if (tid < D) s_ue[tid] = ue_g[u * D + tid];
  if (tid < L) s_it[tid] = items[u * L + tid];
  __syncthreads();

  // short[l][d] = ue[d] + item_emb[items[l]][d] + time_embs[u][l][d]
  for (int idx = tid; idx < L * D; idx += 256) {
    int l = idx >> 6, d = idx & 63;
    s_short[l][d] = s_ue[d] + ie_g[s_it[l] * D + d] + time_embs[(u * L + l) * D + d];
  }
  __syncthreads();

  // Q[l][d] = (short[l] . Wq[:,d]) * (1/sqrt(D))
  for (int idx = tid; idx < L * D; idx += 256) {
    int l = idx >> 6, d = idx & 63;
    float acc = 0.f;
#pragma unroll
    for (int k = 0; k < D; ++k) acc += s_short[l][k] * Wq[k * D + d];
    s_q[l][d] = acc * 0.125f;  // 1/sqrt(64)
  }
  __syncthreads();

  // scores: thread c = tid computes scores[l][c] for all l
  float sc[L];
#pragma unroll
  for (int l = 0; l < L; ++l) sc[l] = 0.f;
  {
    const int c = tid;
#pragma unroll 8
    for (int k = 0; k < D; ++k) {
      float kv = Kmat[c * D + k];
#pragma unroll
      for (int l = 0; l < L; ++l) sc[l] += s_q[l][k] * kv;
    }
  }
  // softmax over c (256 threads): max
#pragma unroll
  for (int l = 0; l < L; ++l) {
    float v = wave_max(sc[l]);
    if (lane == 0) s_red[l][w] = v;
  }
  __syncthreads();
  float e[L];
#pragma unroll
  for (int l = 0; l < L; ++l) {
    float m = fmaxf(fmaxf(s_red[l][0], s_red[l][1]), fmaxf(s_red[l][2], s_red[l][3]));
    e[l] = expf(sc[l] - m);
  }
  __syncthreads();  // s_red reuse
#pragma unroll
  for (int l = 0; l < L; ++l) {
    float v = wave_sum(e[l]);
    if (lane == 0) s_red[l][w] = v;
  }
  __syncthreads();
#pragma unroll
  for (int l = 0; l < L; ++l) {
    float s = (s_red[l][0] + s_red[l][1]) + (s_red[l][2] + s_red[l][3]);
    s_attn[l][tid] = e[l] / s;
  }
  __syncthreads();

  // shorted[l][d] = sum_c attn[l][c] * V[c][d]; V tiled through LDS
  // wave w handles l = w, w+4, w+8(if w<2); lane = d
  float acc0 = 0.f, acc1 = 0.f, acc2 = 0.f;
  for (int ct = 0; ct < C / 64; ++ct) {
    for (int idx = tid; idx < 64 * D; idx += 256) s_vt[idx] = Vmat[ct * 64 * D + idx];
    __syncthreads();
#pragma unroll 16
    for (int c2 = 0; c2 < 64; ++c2) {
      float vv = s_vt[c2 * D + lane];
      int c = ct * 64 + c2;
      acc0 += s_attn[w][c] * vv;
      acc1 += s_attn[w + 4][c] * vv;
      if (w < 2) acc2 += s_attn[w + 8][c] * vv;
    }
    __syncthreads();
  }
  s_shorted[w][lane] = acc0;
  s_shorted[w + 4][lane] = acc1;
  if (w < 2) s_shorted[w + 8][lane] = acc2;
  __syncthreads();

  // s_l = ue . shorted[l]
  for (int l = w; l < L; l += 4) {
    float p = s_ue[lane] * s_shorted[l][lane];
    p = wave_sum(p);
    if (lane == 0) s_sl[l] = p;
  }
  __syncthreads();

  // u_g[d] = a3*(a1*ue[d] + a2 * sum_l s_l[l]*wf[u][l][d])
  if (tid < D) {
    float a1 = *a1p, a2 = *a2p, a3 = *a3p;
    float nu = 0.f;
#pragma unroll
    for (int l = 0; l < L; ++l) nu += s_sl[l] * wf_g[(u * L + l) * D + tid];
    out[b * D + tid] = a3 * (a1 * s_ue[tid] + a2 * nu);
  }
}

extern "C" void kernel_launch(void* const* d_in, const int* in_sizes, int n_in,
                              void* d_out, int out_size, void* d_ws, size_t ws_size,
                              hipStream_t stream) {
  const int* items = (const int*)d_in[0];
  const float* time_embs = (const float*)d_in[1];
  const float* user_emb = (const float*)d_in[2];
  const float* item_emb = (const float*)d_in[3];
  const float* cluster = (const float*)d_in[4];
  const float* wf = (const float*)d_in[5];
  const float* Wq = (const float*)d_in[6];
  const float* Wk = (const float*)d_in[7];
  const float* Wv = (const float*)d_in[8];
  const int* users = (const int*)d_in[9];
  const int* pos = (const int*)d_in[10];
  const int* neg = (const int*)d_in[11];
  const float* a1 = (const float*)d_in[12];
  const float* a2 = (const float*)d_in[13];
  const float* a3 = (const float*)d_in[14];
  const int B = in_sizes[9];

  float* KV = (float*)d_ws;  // K: [C*D], V: [C*D]
  hipLaunchKernelGGL(kv_precompute, dim3((2 * C * D + 255) / 256), dim3(256), 0, stream,
                     cluster, Wk, Wv, KV);
  hipLaunchKernelGGL(filter_main, dim3(B), dim3(256), 0, stream,
                     items, time_embs, user_emb, item_emb, wf, Wq,
                     KV, KV + C * D, users, pos, neg, a1, a2, a3,
                     (float*)d_out, B);
}